// Round 1
// 295.355 us; speedup vs baseline: 1.0117x; 1.0117x over previous
//
#include <hip/hip_runtime.h>
#include <math.h>

#define DD 128
#define KK 8
#define LN_EPS 1e-5f
#define NORM_EPS 1e-12f

typedef __attribute__((ext_vector_type(8))) short bf16x8;
typedef __attribute__((ext_vector_type(16))) float f32x16;
typedef unsigned int uint;
typedef unsigned short ushort;

// exact 3-way bf16 split with RNE (prep only)
__device__ inline void split3(float x, uint& h, uint& m, uint& l) {
    uint u0 = __float_as_uint(x);
    uint rh = (u0 + 0x7FFFu + ((u0 >> 16) & 1u)) & 0xFFFF0000u;
    float xh = __uint_as_float(rh);
    float r1 = x - xh;
    uint u1 = __float_as_uint(r1);
    uint rm = (u1 + 0x7FFFu + ((u1 >> 16) & 1u)) & 0xFFFF0000u;
    float xm = __uint_as_float(rm);
    float r2 = r1 - xm;
    uint u2 = __float_as_uint(r2);
    uint rl = (u2 + 0x7FFFu + ((u2 >> 16) & 1u));
    h = rh; m = rm; l = rl;
}

// cheap truncating 3-way split (main loop); residuals exact, last limb trunc.
__device__ inline void split3t(float x, uint& h, uint& m, uint& l) {
    uint u0 = __float_as_uint(x);
    float xh = __uint_as_float(u0 & 0xFFFF0000u);
    float r1 = x - xh;
    uint u1 = __float_as_uint(r1);
    float xm = __uint_as_float(u1 & 0xFFFF0000u);
    float r2 = r1 - xm;
    h = u0; m = u1; l = __float_as_uint(r2);
}

__device__ inline uint packhi(uint a1, uint a0) {
    return __builtin_amdgcn_perm(a1, a0, 0x07060302u);
}

__device__ inline void split2packt(float e0, float e1, uint& ph, uint& pm, uint& pl) {
    uint h0, m0, l0, h1, m1, l1;
    split3t(e0, h0, m0, l0);
    split3t(e1, h1, m1, l1);
    ph = packhi(h1, h0);
    pm = packhi(m1, m0);
    pl = packhi(l1, l0);
}

union FragU  { uint4 u; bf16x8 f; };
union AccU16 { f32x16 v; float a[16]; };

// ---------------------------------------------------------------------------
// Single persistent kernel. grid = B/1024 = 256 blocks (1 per CU), 1024 thr.
//
// Per block:
//   prep (once): build W_ext (160x128: 128 W rows + 11 folded + 21 zero),
//   RNE 3-way split, pack into 32x32x16 MFMA A-frag layout directly in LDS;
//   scalar tables (g2b, scal) in LDS.
//   main (x2 chunks of 512 rows): 16 waves x 32 rows;
//   D[j_ext][n] = W_ext x x^T via 6-product split-bf16 mfma_32x32x16.
//   Lane: n = lane&31 (x-row), h = lane>>5 (k-half).
//   C/D row = (reg&3)+8*(reg>>2)+4*h.
//   Chunk 0's ks=7 prefetch pulls chunk 1's first x fragments; no barrier
//   between chunks (gath/besti are wave-private; per-wave DS is in-order).
// ---------------------------------------------------------------------------
__global__ __launch_bounds__(1024, 4)
void l1q_all(const float* __restrict__ x, const float* __restrict__ W,
             const float* __restrict__ b, const float* __restrict__ gamma,
             const float* __restrict__ beta, const float* __restrict__ cb,
             float* __restrict__ out_idx, float* __restrict__ out_soft,
             float* __restrict__ out_emb, float* __restrict__ out_log,
             int B)
{
    __shared__ uint4 Wl4[7680];        // 122880 B packed W_ext frags
    __shared__ float gath[16][352];    // [wave][n*11 + local]; aliased as we_s in prep
    __shared__ int   besti[16][32];
    __shared__ float g2b_s[256];
    __shared__ float scal_s[32];
    __shared__ float invn_s[KK];

    ushort* wsA  = (ushort*)Wl4;
    float*  we_s = &gath[0][0];        // 11*128 floats = 5632 B, free until epilogue

    const int t = threadIdx.x;
    const int wave = t >> 6;
    const int lane = t & 63;
    const int n = lane & 31;
    const int h = lane >> 5;

    // chunk-0 x loads issued before prep so latency hides under it
    const float* xp = x + (size_t)(blockIdx.x * 1024 + wave * 32 + n) * DD + h * 8;
    float4 ra = *(const float4*)(xp + 0);
    float4 rc = *(const float4*)(xp + 4);

    // ---------------- phase A: invn, g2b, zero ext tile, pack W tiles 0..3 ----
    if (t < KK) {
        float s = 0.f;
        for (int j = 0; j < DD; ++j) { float v = cb[t * DD + j]; s = fmaf(v, v, s); }
        invn_s[t] = 1.0f / fmaxf(sqrtf(s), NORM_EPS);
    }
    if (t < DD) {
        float g = gamma[t];
        g2b_s[2 * t]     = g * g;
        g2b_s[2 * t + 1] = b[t];
    }
    {
        uint4 z = make_uint4(0u, 0u, 0u, 0u);
        #pragma unroll
        for (int p = 0; p < 2; ++p) {
            int i = t + p * 1024;
            if (i < 1536) {                       // 3 limbs x 8 ks x 64 uint4
                int limb = i >> 9, rem = i & 511;
                Wl4[(limb * 40 + 32) * 64 + rem] = z;
            }
        }
    }
    #pragma unroll
    for (int p = 0; p < 16; ++p) {
        int idx = t + p * 1024;                   // (jl,k) over 128x128
        int jl = idx >> 7, k = idx & 127;
        float v = W[jl * DD + k];
        uint hh, mm, ll; split3(v, hh, mm, ll);
        int jt = jl >> 5, jll = jl & 31, ks = k >> 4, kk = k & 15;
        int lanei = jll + 32 * (kk >> 3), i2 = kk & 7;
        int base = jt * 8 + ks;
        wsA[(0 * 40 + base) * 512 + lanei * 8 + i2] = (ushort)(hh >> 16);
        wsA[(1 * 40 + base) * 512 + lanei * 8 + i2] = (ushort)(mm >> 16);
        wsA[(2 * 40 + base) * 512 + lanei * 8 + i2] = (ushort)(ll >> 16);
    }
    __syncthreads();

    // ---------------- phase B: folded-row weights we[11][128] + scal table ----
    for (int idx = t; idx < 11 * DD; idx += 1024) {
        int e = idx >> 7, j = idx & 127;
        float g = gamma[j];
        float v;
        if (e == 0)      v = 1.0f;
        else if (e == 1) v = g * g;
        else if (e == 2) v = g * beta[j];
        else             v = cb[(e - 3) * DD + j] * invn_s[e - 3] * g;
        we_s[idx] = v;
    }
    if (t < KK) {
        float in = invn_s[t];
        float p = 0.f, q = 0.f, cu = 0.f;
        for (int j = 0; j < DD; ++j) {
            float c = cb[t * DD + j] * in;
            p  = fmaf(c, gamma[j], p);
            q  = fmaf(c, beta[j], q);
            cu = fmaf(c * gamma[j], b[j], cu);
        }
        scal_s[t]      = p;   // pk
        scal_s[8 + t]  = q;   // q0k
        scal_s[22 + t] = cu;  // cuk
    }
    if (t == 16) { float s = 0.f; for (int j = 0; j < DD; ++j) { float g = gamma[j]; s = fmaf(g, g, s); } scal_s[16] = s; }
    if (t == 17) { float s = 0.f; for (int j = 0; j < DD; ++j) s = fmaf(gamma[j], beta[j], s); scal_s[17] = s; }
    if (t == 18) { float s = 0.f; for (int j = 0; j < DD; ++j) { float v = beta[j]; s = fmaf(v, v, s); } scal_s[18] = s; }
    if (t == 19) { float s = 0.f; for (int j = 0; j < DD; ++j) s += b[j]; scal_s[19] = s; }                              // cs1
    if (t == 20) { float s = 0.f; for (int j = 0; j < DD; ++j) s = fmaf(gamma[j] * gamma[j], b[j], s); scal_s[20] = s; } // ct1
    if (t == 21) { float s = 0.f; for (int j = 0; j < DD; ++j) s = fmaf(gamma[j] * beta[j], b[j], s); scal_s[21] = s; }  // cr1
    __syncthreads();

    // ---------------- phase C: folded rows (ext tile rows 0..10) -------------
    #pragma unroll
    for (int p = 0; p < 2; ++p) {
        int idx = t + p * 1024;                   // (e,k) over 11x128
        if (idx < 11 * DD) {
            int e = idx >> 7, k = idx & 127;
            float s = 0.f;
            for (int j = 0; j < DD; ++j) s = fmaf(we_s[e * DD + j], W[j * DD + k], s);
            uint hh, mm, ll; split3(s, hh, mm, ll);
            int ks = k >> 4, kk = k & 15;
            int lanei = e + 32 * (kk >> 3), i2 = kk & 7;
            int base = 32 + ks;                   // jt = 4
            wsA[(0 * 40 + base) * 512 + lanei * 8 + i2] = (ushort)(hh >> 16);
            wsA[(1 * 40 + base) * 512 + lanei * 8 + i2] = (ushort)(mm >> 16);
            wsA[(2 * 40 + base) * 512 + lanei * 8 + i2] = (ushort)(ll >> 16);
        }
    }
    __syncthreads();

    // ---------------- main: 2 chunks of 512 rows ------------------------------
    const float inv128 = 1.0f / 128.0f;

    #pragma unroll 1
    for (int c = 0; c < 2; ++c) {
        const int rowbase = blockIdx.x * 1024 + c * 512 + wave * 32;
        const float* xnext = (c == 0) ? (xp + 512 * DD) : xp;

        f32x16 acc[5];
        #pragma unroll
        for (int jt = 0; jt < 5; ++jt)
            #pragma unroll
            for (int r = 0; r < 16; ++r) acc[jt][r] = 0.f;

        #pragma unroll
        for (int ks = 0; ks < 8; ++ks) {
            const float* pf = (ks < 7) ? (xp + (ks + 1) * 16) : xnext;
            float4 na = *(const float4*)(pf + 0);
            float4 nc = *(const float4*)(pf + 4);

            FragU xh, xm, xl;
            split2packt(ra.x, ra.y, xh.u.x, xm.u.x, xl.u.x);
            split2packt(ra.z, ra.w, xh.u.y, xm.u.y, xl.u.y);
            split2packt(rc.x, rc.y, xh.u.z, xm.u.z, xl.u.z);
            split2packt(rc.z, rc.w, xh.u.w, xm.u.w, xl.u.w);

            #pragma unroll
            for (int jt = 0; jt < 5; ++jt) {
                const int pl = jt * 8 + ks;
                FragU wh, wm, wl;
                wh.u = Wl4[(0 * 40 + pl) * 64 + lane];
                wm.u = Wl4[(1 * 40 + pl) * 64 + lane];
                wl.u = Wl4[(2 * 40 + pl) * 64 + lane];
                f32x16 cacc = acc[jt];
                cacc = __builtin_amdgcn_mfma_f32_32x32x16_bf16(wl.f, xh.f, cacc, 0, 0, 0);
                cacc = __builtin_amdgcn_mfma_f32_32x32x16_bf16(wh.f, xl.f, cacc, 0, 0, 0);
                cacc = __builtin_amdgcn_mfma_f32_32x32x16_bf16(wm.f, xm.f, cacc, 0, 0, 0);
                cacc = __builtin_amdgcn_mfma_f32_32x32x16_bf16(wm.f, xh.f, cacc, 0, 0, 0);
                cacc = __builtin_amdgcn_mfma_f32_32x32x16_bf16(wh.f, xm.f, cacc, 0, 0, 0);
                cacc = __builtin_amdgcn_mfma_f32_32x32x16_bf16(wh.f, xh.f, cacc, 0, 0, 0);
                acc[jt] = cacc;
            }
            ra = na; rc = nc;
        }

        // ---- quadratic sums over true W rows (jt 0..3) ----
        float s2a = 0.f, t2a = 0.f;
        #pragma unroll
        for (int jt = 0; jt < 4; ++jt) {
            AccU16 a; a.v = acc[jt];
            #pragma unroll
            for (int rq = 0; rq < 4; ++rq) {
                int jb = jt * 32 + 8 * rq + 4 * h;
                #pragma unroll
                for (int r = 0; r < 4; ++r) {
                    float2 gb = *(const float2*)&g2b_s[2 * (jb + r)];
                    float hv = a.a[rq * 4 + r] + gb.y;
                    float h2 = hv * hv;
                    s2a += h2;
                    t2a = fmaf(gb.x, h2, t2a);
                }
            }
        }
        s2a += __shfl_xor(s2a, 32);
        t2a += __shfl_xor(t2a, 32);

        // ---- gather 11 folded linear sums (tile jt=4, locals 0..10) ----
        {
            AccU16 a; a.v = acc[4];
            #pragma unroll
            for (int rq = 0; rq < 4; ++rq) {
                #pragma unroll
                for (int r = 0; r < 4; ++r) {
                    int local = r + 8 * rq + 4 * h;
                    if (local < 11) gath[wave][n * 11 + local] = a.a[rq * 4 + r];
                }
            }
        }
        __builtin_amdgcn_s_waitcnt(0);   // wave-internal LDS ordering
        const float* gp = &gath[wave][n * 11];

        const float cg2s = scal_s[16], cgbs = scal_s[17], cb2s = scal_s[18];

        float s1  = gp[0] + scal_s[19];
        float t1  = gp[1] + scal_s[20];
        float r1v = gp[2] + scal_s[21];
        float u[KK];
        #pragma unroll
        for (int k = 0; k < KK; ++k) u[k] = gp[3 + k] + scal_s[22 + k];

        float mu = s1 * inv128;
        float var = fmaf(-mu, mu, s2a * inv128);
        float istd = 1.0f / sqrtf(var + LN_EPS);
        float nrm2 = istd * istd * (t2a - 2.f * mu * t1 + mu * mu * cg2s)
                   + 2.f * istd * (r1v - mu * cgbs) + cb2s;
        float rinv = 1.0f / fmaxf(sqrtf(fmaxf(nrm2, 0.f)), NORM_EPS);

        float lg[KK];
        #pragma unroll
        for (int k = 0; k < KK; ++k)
            lg[k] = (istd * (u[k] - mu * scal_s[k]) + scal_s[8 + k]) * rinv;

        float mx = lg[0]; int bi = 0;
        #pragma unroll
        for (int k = 1; k < KK; ++k) if (lg[k] > mx) { mx = lg[k]; bi = k; }

        float ex[KK], se = 0.f;
        #pragma unroll
        for (int k = 0; k < KK; ++k) { ex[k] = expf(lg[k] - mx); se += ex[k]; }
        float rse = 1.0f / se;

        const int m = rowbase + n;
        if (h == 0) {
            out_idx[m] = (float)bi;
            besti[wave][n] = bi;
            *(float4*)&out_log[(size_t)m * KK]     = make_float4(lg[0], lg[1], lg[2], lg[3]);
            *(float4*)&out_log[(size_t)m * KK + 4] = make_float4(lg[4], lg[5], lg[6], lg[7]);
        } else {
            *(float4*)&out_soft[(size_t)m * KK]     = make_float4(ex[0] * rse, ex[1] * rse, ex[2] * rse, ex[3] * rse);
            *(float4*)&out_soft[(size_t)m * KK + 4] = make_float4(ex[4] * rse, ex[5] * rse, ex[6] * rse, ex[7] * rse);
        }

        // ---- embedding: emb[row] = codebook[best[row]], coalesced per wave ----
        __builtin_amdgcn_s_waitcnt(0);
        const float4* cb4 = (const float4*)cb;
        float4* eo = (float4*)out_emb;
        #pragma unroll
        for (int i = 0; i < 16; ++i) {
            int f4 = lane + 64 * i;          // 0..1023 over 32 rows x 32 float4
            int rl = f4 >> 5;
            int cc = f4 & 31;
            int k0 = besti[wave][rl];
            eo[(size_t)(rowbase + rl) * 32 + cc] = cb4[k0 * 32 + cc];
        }

        xp = xnext;
    }
}

extern "C" void kernel_launch(void* const* d_in, const int* in_sizes, int n_in,
                              void* d_out, int out_size, void* d_ws, size_t ws_size,
                              hipStream_t stream) {
    const float* x     = (const float*)d_in[0];
    const float* W     = (const float*)d_in[1];
    const float* b     = (const float*)d_in[2];
    const float* gamma = (const float*)d_in[3];
    const float* beta  = (const float*)d_in[4];
    const float* cb    = (const float*)d_in[5];
    const int B = in_sizes[0] / DD;

    float* out    = (float*)d_out;
    float* o_idx  = out;
    float* o_soft = out + (size_t)B;
    float* o_emb  = out + (size_t)B * (1 + KK);
    float* o_log  = out + (size_t)B * (1 + KK + DD);

    const int grid = B / 1024;   // 256 blocks: exactly 1 per CU, 2x512-row chunks
    hipLaunchKernelGGL(l1q_all, dim3(grid), dim3(1024), 0, stream,
                       x, W, b, gamma, beta, cb, o_idx, o_soft, o_emb, o_log, B);
}